// Round 2
// baseline (1984.357 us; speedup 1.0000x reference)
//
#include <hip/hip_runtime.h>
#include <hip/hip_fp16.h>

typedef _Float16 f16;
typedef __attribute__((ext_vector_type(2))) _Float16 f16x2;
typedef __attribute__((ext_vector_type(4))) _Float16 f16x4;
typedef __attribute__((ext_vector_type(8))) _Float16 f16x8;
typedef __attribute__((ext_vector_type(4))) float f32x4;

constexpr int BATCH = 64;
constexpr int TLEN  = 2048;
constexpr int NIN   = 128;
constexpr int NHID  = 256;
constexpr int NOUT  = 128;
constexpr long MROWS = (long)BATCH * TLEN;   // 131072
constexpr float CSC = 2.8853900817779268f;   // 2*log2(e): 2^(CSC*z) = e^(2z)

__device__ __forceinline__ float exp2f_hw(float x) {
#if __has_builtin(__builtin_amdgcn_exp2f)
  return __builtin_amdgcn_exp2f(x);
#else
  return __expf(x * 0.6931471805599453f);
#endif
}
__device__ __forceinline__ float rcp_hw(float x) {
#if __has_builtin(__builtin_amdgcn_rcpf)
  return __builtin_amdgcn_rcpf(x);
#else
  return 1.0f / x;
#endif
}
// barrier that makes LDS writes visible WITHOUT draining vmcnt (global
// stores / prefetch loads keep flying across steps)
__device__ __forceinline__ void barrier_lds() {
  asm volatile("s_waitcnt lgkmcnt(0)" ::: "memory");
  __builtin_amdgcn_s_barrier();
  asm volatile("" ::: "memory");
}

// ---------------------------------------------------------------------------
// Weight convert + hi/lo split. Whh pre-scaled by CSC (tanh exp2 fold).
// f16 layout: WinH[32768] WinL[32768] WihH[65536] WihL[65536] Whh[65536] Wout[32768]
// ---------------------------------------------------------------------------
__global__ void cvt_weights(const float* __restrict__ Win, const float* __restrict__ Wih,
                            const float* __restrict__ Whh, const float* __restrict__ Wout,
                            f16* __restrict__ dst) {
  int i = blockIdx.x * blockDim.x + threadIdx.x;
  if (i < 32768) {
    float v = Win[i]; f16 h = (f16)v;
    dst[i] = h; dst[32768 + i] = (f16)(v - (float)h);
  } else if (i < 98304) {
    int j = i - 32768; float v = Wih[j]; f16 h = (f16)v;
    dst[65536 + j] = h; dst[131072 + j] = (f16)(v - (float)h);
  } else if (i < 163840) {
    int j = i - 98304; dst[196608 + j] = (f16)(CSC * Whh[j]);
  } else if (i < 196608) {
    int j = i - 163840; dst[262144 + j] = (f16)Wout[j];
  }
}

// ---------------------------------------------------------------------------
// GEMM: C[m,n] = act( sum_k A[m,k]*W[n,k] + bias[n] )
// MODE 2: pre is stored [t][b][o] (prow = t*64 + b) so the MFMA recurrence
// can load per-step pre as contiguous float4 accumulator inits.
// ---------------------------------------------------------------------------
constexpr int BM = 64, BN = 64, BK = 64;

template<int MODE>
__global__ __launch_bounds__(256)
void gemm_kernel(const void* __restrict__ Ap, const void* __restrict__ Ap2,
                 const f16* __restrict__ Bh_, const f16* __restrict__ Bl_,
                 const float* __restrict__ bias, const float* __restrict__ bias2,
                 void* __restrict__ Cp, void* __restrict__ Cp2,
                 int K, int N) {
  __shared__ __align__(16) f16 Ah[BM][BK + 8];
  __shared__ __align__(16) f16 Al[BM][BK + 8];
  __shared__ __align__(16) f16 Bh[BN][BK + 8];
  __shared__ __align__(16) f16 Bl[BN][BK + 8];

  const int tid  = threadIdx.x;
  const int lane = tid & 63;
  const int wid  = tid >> 6;
  const int wm = wid >> 1, wn = wid & 1;
  const long row0 = (long)blockIdx.x * BM;
  const int  col0 = blockIdx.y * BN;
  const int r  = tid >> 2;
  const int cc = (tid & 3) * 16;

  f32x4 acc[2][2] = {};

  for (int k0 = 0; k0 < K; k0 += BK) {
    if constexpr (MODE == 1) {
      const float* src = (const float*)Ap + (row0 + r) * (long)K + k0 + cc;
      #pragma unroll
      for (int q = 0; q < 4; ++q) {
        float4 v = ((const float4*)src)[q];
        f16 h0 = (f16)v.x, h1 = (f16)v.y, h2 = (f16)v.z, h3 = (f16)v.w;
        Ah[r][cc + 4*q + 0] = h0;  Al[r][cc + 4*q + 0] = (f16)(v.x - (float)h0);
        Ah[r][cc + 4*q + 1] = h1;  Al[r][cc + 4*q + 1] = (f16)(v.y - (float)h1);
        Ah[r][cc + 4*q + 2] = h2;  Al[r][cc + 4*q + 2] = (f16)(v.z - (float)h2);
        Ah[r][cc + 4*q + 3] = h3;  Al[r][cc + 4*q + 3] = (f16)(v.w - (float)h3);
      }
    } else if constexpr (MODE == 2) {
      const f16* sh = (const f16*)Ap  + (row0 + r) * (long)K + k0 + cc;
      const f16* sl = (const f16*)Ap2 + (row0 + r) * (long)K + k0 + cc;
      *(uint4*)&Ah[r][cc]     = *(const uint4*)sh;
      *(uint4*)&Ah[r][cc + 8] = *(const uint4*)(sh + 8);
      *(uint4*)&Al[r][cc]     = *(const uint4*)sl;
      *(uint4*)&Al[r][cc + 8] = *(const uint4*)(sl + 8);
    } else {
      const f16* sh = (const f16*)Ap + (row0 + r) * (long)K + k0 + cc;
      *(uint4*)&Ah[r][cc]     = *(const uint4*)sh;
      *(uint4*)&Ah[r][cc + 8] = *(const uint4*)(sh + 8);
    }
    {
      const f16* sh = Bh_ + (col0 + r) * (long)K + k0 + cc;
      *(uint4*)&Bh[r][cc]     = *(const uint4*)sh;
      *(uint4*)&Bh[r][cc + 8] = *(const uint4*)(sh + 8);
      if constexpr (MODE != 3) {
        const f16* sl = Bl_ + (col0 + r) * (long)K + k0 + cc;
        *(uint4*)&Bl[r][cc]     = *(const uint4*)sl;
        *(uint4*)&Bl[r][cc + 8] = *(const uint4*)(sl + 8);
      }
    }
    __syncthreads();

    #pragma unroll
    for (int ks = 0; ks < BK / 32; ++ks) {
      const int ko = ks * 32 + (lane >> 4) * 8;
      const int ra = wm * 32 + (lane & 15);
      const int rb = wn * 32 + (lane & 15);
      f16x8 a0 = *(const f16x8*)&Ah[ra][ko];
      f16x8 a1 = *(const f16x8*)&Ah[ra + 16][ko];
      f16x8 b0 = *(const f16x8*)&Bh[rb][ko];
      f16x8 b1 = *(const f16x8*)&Bh[rb + 16][ko];
      acc[0][0] = __builtin_amdgcn_mfma_f32_16x16x32_f16(a0, b0, acc[0][0], 0, 0, 0);
      acc[0][1] = __builtin_amdgcn_mfma_f32_16x16x32_f16(a0, b1, acc[0][1], 0, 0, 0);
      acc[1][0] = __builtin_amdgcn_mfma_f32_16x16x32_f16(a1, b0, acc[1][0], 0, 0, 0);
      acc[1][1] = __builtin_amdgcn_mfma_f32_16x16x32_f16(a1, b1, acc[1][1], 0, 0, 0);
      if constexpr (MODE != 3) {
        f16x8 la0 = *(const f16x8*)&Al[ra][ko];
        f16x8 la1 = *(const f16x8*)&Al[ra + 16][ko];
        f16x8 lb0 = *(const f16x8*)&Bl[rb][ko];
        f16x8 lb1 = *(const f16x8*)&Bl[rb + 16][ko];
        acc[0][0] = __builtin_amdgcn_mfma_f32_16x16x32_f16(a0, lb0, acc[0][0], 0, 0, 0);
        acc[0][0] = __builtin_amdgcn_mfma_f32_16x16x32_f16(la0, b0, acc[0][0], 0, 0, 0);
        acc[0][1] = __builtin_amdgcn_mfma_f32_16x16x32_f16(a0, lb1, acc[0][1], 0, 0, 0);
        acc[0][1] = __builtin_amdgcn_mfma_f32_16x16x32_f16(la0, b1, acc[0][1], 0, 0, 0);
        acc[1][0] = __builtin_amdgcn_mfma_f32_16x16x32_f16(a1, lb0, acc[1][0], 0, 0, 0);
        acc[1][0] = __builtin_amdgcn_mfma_f32_16x16x32_f16(la1, b0, acc[1][0], 0, 0, 0);
        acc[1][1] = __builtin_amdgcn_mfma_f32_16x16x32_f16(a1, lb1, acc[1][1], 0, 0, 0);
        acc[1][1] = __builtin_amdgcn_mfma_f32_16x16x32_f16(la1, b1, acc[1][1], 0, 0, 0);
      }
    }
    __syncthreads();
  }

  #pragma unroll
  for (int mi = 0; mi < 2; ++mi)
    #pragma unroll
    for (int ni = 0; ni < 2; ++ni)
      #pragma unroll
      for (int q = 0; q < 4; ++q) {
        long row = row0 + wm * 32 + mi * 16 + (lane >> 4) * 4 + q;
        int  col = col0 + wn * 32 + ni * 16 + (lane & 15);
        if constexpr (MODE == 1) {
          float v = fmaxf(acc[mi][ni][q] + bias[col], 0.0f);
          f16 h = (f16)v;
          ((f16*)Cp )[row * (long)N + col] = h;
          ((f16*)Cp2)[row * (long)N + col] = (f16)(v - (float)h);
        } else if constexpr (MODE == 2) {
          float v = (acc[mi][ni][q] + bias[col] + bias2[col]) * CSC;
          long prow = (row & (long)(TLEN - 1)) * BATCH + (row >> 11);  // [t][b]
          ((float*)Cp)[prow * (long)N + col] = v;
        } else {
          ((float*)Cp)[row * (long)N + col] = acc[mi][ni][q] + bias[col];
        }
      }
}

// ---------------------------------------------------------------------------
// Recurrence R14 = R13 (MFMA-pipe matvec) with the read-swizzle bug fixed.
//
// 8 blocks x 512 threads; block = 8 batches (b = 8*blk + col, col = lane&15,
// valid cols 0..7). Per step: D[o, b] = sum_k W[o,k] * H[b,k] via
// mfma_f32_16x16x32_f16 (A = W rows, stationary in 64 VGPRs/lane; B = H from
// 8 KB ping-pong LDS, b128 fragment reads, exec-masked to 32 valid lanes).
// acc initialized directly from prefetched pre (layout [t][b][o]: D-frag
// q-axis == 4 consecutive o for fixed b == one float4). K split into two
// 4-deep MFMA chains. LDS swizzle: phys = logical ^ ((b&7)<<4) on in-row
// bits 4..6, decomposed into disjoint bit fields:
//   write (b, o=32w+16t+4kg): b*512 + (8kg ^ ((b&1)<<4)) + ((b&2)<<4)
//                             + (64w ^ ((b&4)<<4)), tile1 = ^32
//   read  (b, k=c*32+kg*8):   roff[c] = [b*512 + (kg*16 ^ ((b&3)<<4))
//                             + ((b&4)<<4)] ^ (c*64)
// R13 BUG (absmax 0.566): read side used "+ ((b&4)<<4) + c*64" — ADD instead
// of XOR on bit 6. For odd c with b&4 this reads chunk c+1 instead of c-1
// (and c=7 crossed into the other ping-pong buffer) -> half the batches got
// corrupt H every step. Fixed by precomputing roff[c] = rbase ^ (c*64)
// (rbase has no other bits 6..8 content, so XOR with the compile-time c*64
// is exactly the intended bijection; 8 XORs once, loop codegen unchanged).
// 4-step unroll, 4-deep pre prefetch (guarded), lgkmcnt-only barriers.
// h16 layout [b][t][o] unchanged -> cvt_h and gemm3 untouched.
// ---------------------------------------------------------------------------
#define RSTEP(S, SO, DO_, P0, P1) do {                                        \
  if (valid) {                                                                \
    _Pragma("unroll")                                                         \
    for (int c = 0; c < 8; ++c)                                               \
      hB[c] = *(const f16x8*)(hbase + (SO) + roff[c]);                        \
  }                                                                           \
  f32x4 aA0 = (P0), aA1 = (P1);                                               \
  f32x4 aB0 = {0.f, 0.f, 0.f, 0.f};                                           \
  f32x4 aB1 = {0.f, 0.f, 0.f, 0.f};                                           \
  _Pragma("unroll")                                                           \
  for (int c = 0; c < 4; ++c) {                                               \
    aA0 = __builtin_amdgcn_mfma_f32_16x16x32_f16(wA[0][c],     hB[c],     aA0, 0, 0, 0); \
    aA1 = __builtin_amdgcn_mfma_f32_16x16x32_f16(wA[1][c],     hB[c],     aA1, 0, 0, 0); \
    aB0 = __builtin_amdgcn_mfma_f32_16x16x32_f16(wA[0][c + 4], hB[c + 4], aB0, 0, 0, 0); \
    aB1 = __builtin_amdgcn_mfma_f32_16x16x32_f16(wA[1][c + 4], hB[c + 4], aB1, 0, 0, 0); \
  }                                                                           \
  f16x4 h0, h1;                                                               \
  _Pragma("unroll")                                                           \
  for (int q = 0; q < 4; ++q) {                                               \
    float z0 = aA0[q] + aB0[q];                                               \
    float z1 = aA1[q] + aB1[q];                                               \
    float e0 = exp2f_hw(z0);                                                  \
    float e1 = exp2f_hw(z1);                                                  \
    float v0 = fmaxf(fmaf(-2.0f, rcp_hw(e0 + 1.0f), 1.0f), 0.0f);             \
    float v1 = fmaxf(fmaf(-2.0f, rcp_hw(e1 + 1.0f), 1.0f), 0.0f);             \
    h0[q] = (f16)v0;                                                          \
    h1[q] = (f16)v1;                                                          \
  }                                                                           \
  if (valid) {                                                                \
    *(f16x4*)(hbase + (DO_) + wb0) = h0;       /* LDS next-h, tile 0 */       \
    *(f16x4*)(hbase + (DO_) + wb1) = h1;       /* LDS next-h, tile 1 */       \
    *(f16x4*)(hp + (S) * 256)      = h0;       /* h16 global  tile 0 */       \
    *(f16x4*)(hp + (S) * 256 + 16) = h1;       /* h16 global  tile 1 */       \
  }                                                                           \
  barrier_lds();                                                              \
} while (0)

__global__ __launch_bounds__(512, 1)
void rec_mfma(const float* __restrict__ pre, const f16* __restrict__ Whh,
              f16* __restrict__ h16) {
  const int blk  = blockIdx.x;          // 0..7 -> batches 8*blk .. 8*blk+7
  const int tid  = threadIdx.x;
  const int lane = tid & 63;
  const int w    = tid >> 6;            // wave 0..7: outputs [32w, 32w+32)
  const int col  = lane & 15;           // MFMA n-col = batch slot (valid < 8)
  const int kg   = lane >> 4;           // 0..3: k-subgroup / D-row group
  const bool valid = (col < 8);
  const int bq   = col & 7;             // clamped batch slot (addr-safe)
  const long bglob = (long)blk * 8 + bq;

  __shared__ __align__(16) char hb[8192];   // 2 ping-pong h buffers, 4 KB each
  char* hbase = (char*)hb;

  // Stationary W fragments: A[m=o][k]; lane holds m = col, k = c*32+kg*8 .. +8
  f16x8 wA[2][8];
  #pragma unroll
  for (int t = 0; t < 2; ++t)
    #pragma unroll
    for (int c = 0; c < 8; ++c)
      wA[t][c] = *(const f16x8*)(Whh + (size_t)(32 * w + 16 * t + col) * 256
                                 + c * 32 + kg * 8);

  // zero both h buffers (h_0 = 0; also keeps never-written bytes finite)
  {
    uint4 z = {0u, 0u, 0u, 0u};
    *(uint4*)(hbase + tid * 16) = z;
  }
  __syncthreads();

  // swizzled LDS offsets (see header comment)
  const int rbase = bq * 512 + ((kg * 16) ^ ((bq & 3) << 4)) + ((bq & 4) << 4);
  int roff[8];
  #pragma unroll
  for (int c = 0; c < 8; ++c) roff[c] = rbase ^ (c * 64);   // true bit-6 XOR
  const int wb0   = bq * 512 + ((8 * kg) ^ ((bq & 1) << 4)) + ((bq & 2) << 4)
                  + ((64 * w) ^ ((bq & 4) << 4));
  const int wb1   = wb0 ^ 32;

  const float* pp  = pre + (size_t)bglob * 256 + 32 * w + 4 * kg;
  f16*         hp  = h16 + (size_t)bglob * TLEN * 256 + 32 * w + 4 * kg;
  const float* ppf = pp + 4 * 16384;    // t+4 prefetch pointer (16384 f32/step)

  f32x4 p00 = *(const f32x4*)(pp);
  f32x4 p01 = *(const f32x4*)(pp + 16);
  f32x4 p10 = *(const f32x4*)(pp + 16384);
  f32x4 p11 = *(const f32x4*)(pp + 16400);
  f32x4 p20 = *(const f32x4*)(pp + 32768);
  f32x4 p21 = *(const f32x4*)(pp + 32784);
  f32x4 p30 = *(const f32x4*)(pp + 49152);
  f32x4 p31 = *(const f32x4*)(pp + 49168);

  f16x8 hB[8] = {};   // invalid-col lanes keep zeros forever (garbage D cols only)

  #pragma unroll 1
  for (int t = 0; t < TLEN; t += 4) {
    f32x4 n00 = {}, n01 = {}, n10 = {}, n11 = {};
    f32x4 n20 = {}, n21 = {}, n30 = {}, n31 = {};
    if (t + 4 < TLEN) {               // uniform guard: stride is 64 KB/step
      n00 = *(const f32x4*)(ppf);
      n01 = *(const f32x4*)(ppf + 16);
      n10 = *(const f32x4*)(ppf + 16384);
      n11 = *(const f32x4*)(ppf + 16400);
      n20 = *(const f32x4*)(ppf + 32768);
      n21 = *(const f32x4*)(ppf + 32784);
      n30 = *(const f32x4*)(ppf + 49152);
      n31 = *(const f32x4*)(ppf + 49168);
    }
    RSTEP(0, 0,    4096, p00, p01);
    RSTEP(1, 4096, 0,    p10, p11);
    RSTEP(2, 0,    4096, p20, p21);
    RSTEP(3, 4096, 0,    p30, p31);
    p00 = n00; p01 = n01; p10 = n10; p11 = n11;
    p20 = n20; p21 = n21; p30 = n30; p31 = n31;
    ppf += 65536;
    hp  += 1024;
  }
}

// ---------------------------------------------------------------------------
// h16 -> f32 hidden (parallel, HBM-bound). Unchanged.
// ---------------------------------------------------------------------------
__global__ __launch_bounds__(256)
void cvt_h(const f16* __restrict__ src, float* __restrict__ dst, long n) {
  long i0 = ((long)blockIdx.x * 256 + threadIdx.x) * 8;
  long stride = (long)gridDim.x * 256 * 8;
  for (long i = i0; i < n; i += stride) {
    f16x8 v = *(const f16x8*)(src + i);
    float4 a = {(float)v[0], (float)v[1], (float)v[2], (float)v[3]};
    float4 bq = {(float)v[4], (float)v[5], (float)v[6], (float)v[7]};
    *(float4*)(dst + i) = a;
    *(float4*)(dst + i + 4) = bq;
  }
}

// ---------------------------------------------------------------------------
extern "C" void kernel_launch(void* const* d_in, const int* in_sizes, int n_in,
                              void* d_out, int out_size, void* d_ws, size_t ws_size,
                              hipStream_t stream) {
  const float* input = (const float*)d_in[0];
  const float* W_in  = (const float*)d_in[1];
  const float* b_in  = (const float*)d_in[2];
  const float* W_ih  = (const float*)d_in[3];
  const float* b_ih  = (const float*)d_in[4];
  const float* W_hh  = (const float*)d_in[5];
  const float* b_hh  = (const float*)d_in[6];
  const float* W_out = (const float*)d_in[7];
  const float* b_out = (const float*)d_in[8];

  float* hidden = (float*)d_out;                   // [64,2048,256] f32
  float* outp   = (float*)d_out + MROWS * NHID;    // [64,2048,128] f32

  char* ws = (char*)d_ws;
  const size_t xh_off  = 0;
  const size_t xl_off  = (size_t)MROWS * NHID * 2;       // 64 MiB
  const size_t pre_off = xl_off * 2;                     // 128 MiB in
  const size_t w_off   = pre_off + (size_t)MROWS * NHID * 4;
  const size_t need    = w_off + 294912ull * 2;
  if (ws_size < need) return;

  f16*   x_hi  = (f16*)(ws + xh_off);
  f16*   x_lo  = (f16*)(ws + xl_off);
  float* pre   = (float*)(ws + pre_off);                 // [t][b][g], CSC-scaled
  f16*   wbase = (f16*)(ws + w_off);
  f16 *WinH = wbase,           *WinL = wbase + 32768;
  f16 *WihH = wbase + 65536,   *WihL = wbase + 131072;
  f16 *Whh16 = wbase + 196608, *Wout16 = wbase + 262144;
  f16* h16 = x_hi;   // alias: x consumed by G2 before rec writes h16

  cvt_weights<<<768, 256, 0, stream>>>(W_in, W_ih, W_hh, W_out, wbase);

  dim3 g12((unsigned)(MROWS / BM), NHID / BN);
  gemm_kernel<1><<<g12, 256, 0, stream>>>(input, nullptr, WinH, WinL, b_in, nullptr,
                                          x_hi, x_lo, NIN, NHID);
  gemm_kernel<2><<<g12, 256, 0, stream>>>(x_hi, x_lo, WihH, WihL, b_ih, b_hh,
                                          pre, nullptr, NHID, NHID);

  rec_mfma<<<8, 512, 0, stream>>>(pre, Whh16, h16);

  cvt_h<<<2048, 256, 0, stream>>>(h16, hidden, MROWS * NHID);

  dim3 g3((unsigned)(MROWS / BM), NOUT / BN);
  gemm_kernel<3><<<g3, 256, 0, stream>>>(h16, nullptr, Wout16, nullptr, b_out, nullptr,
                                         outp, nullptr, NHID, NOUT);
}

// Round 3
// 1194.413 us; speedup vs baseline: 1.6614x; 1.6614x over previous
//
#include <hip/hip_runtime.h>
#include <hip/hip_fp16.h>

typedef _Float16 f16;
typedef __attribute__((ext_vector_type(2))) _Float16 f16x2;
typedef __attribute__((ext_vector_type(8))) _Float16 f16x8;
typedef __attribute__((ext_vector_type(4))) float f32x4;

constexpr int BATCH = 64;
constexpr int TLEN  = 2048;
constexpr int NIN   = 128;
constexpr int NHID  = 256;
constexpr int NOUT  = 128;
constexpr long MROWS = (long)BATCH * TLEN;   // 131072
constexpr float CSC = 2.8853900817779268f;   // 2*log2(e): 2^(CSC*z) = e^(2z)

__device__ __forceinline__ float exp2f_hw(float x) {
#if __has_builtin(__builtin_amdgcn_exp2f)
  return __builtin_amdgcn_exp2f(x);
#else
  return __expf(x * 0.6931471805599453f);
#endif
}
__device__ __forceinline__ float rcp_hw(float x) {
#if __has_builtin(__builtin_amdgcn_rcpf)
  return __builtin_amdgcn_rcpf(x);
#else
  return 1.0f / x;
#endif
}
__device__ __forceinline__ float fdot2f(unsigned int a, unsigned int b, float c) {
#if __has_builtin(__builtin_amdgcn_fdot2)
  return __builtin_amdgcn_fdot2(__builtin_bit_cast(f16x2, a),
                                __builtin_bit_cast(f16x2, b), c, false);
#else
  f16x2 av = __builtin_bit_cast(f16x2, a);
  f16x2 bv = __builtin_bit_cast(f16x2, b);
  return c + (float)av.x * (float)bv.x + (float)av.y * (float)bv.y;
#endif
}
// DPP: 0xB1 = quad_perm(1,0,3,2) -> lane^1 ; 0x4E = quad_perm(2,3,0,1) -> lane^2
template<int CTRL>
__device__ __forceinline__ float dpp_xor(float x) {
  int r = __builtin_amdgcn_update_dpp(0, __builtin_bit_cast(int, x),
                                      CTRL, 0xF, 0xF, true);
  return __builtin_bit_cast(float, r);
}
// partner value across lane^32 (VALU permlane on gfx950; LDS bpermute fallback)
__device__ __forceinline__ float xor32_partner(float x, int lane) {
#if __has_builtin(__builtin_amdgcn_permlane32_swap)
  auto r = __builtin_amdgcn_permlane32_swap(
      __builtin_bit_cast(unsigned int, x), __builtin_bit_cast(unsigned int, x),
      false, false);
  unsigned int pv = (lane < 32) ? r[1] : r[0];  // r[0]=new_vdst, r[1]=new_src0
  return __builtin_bit_cast(float, pv);
#else
  return __builtin_bit_cast(float, __builtin_amdgcn_ds_bpermute(
      ((lane ^ 32) << 2), __builtin_bit_cast(int, x)));
#endif
}
// barrier that makes LDS writes visible WITHOUT draining vmcnt (global
// stores / prefetch loads keep flying across steps)
__device__ __forceinline__ void barrier_lds() {
  asm volatile("s_waitcnt lgkmcnt(0)" ::: "memory");
  __builtin_amdgcn_s_barrier();
  asm volatile("" ::: "memory");
}

// ---------------------------------------------------------------------------
// Weight convert + hi/lo split. Whh pre-scaled by CSC (tanh exp2 fold).
// f16 layout: WinH[32768] WinL[32768] WihH[65536] WihL[65536] Whh[65536] Wout[32768]
// ---------------------------------------------------------------------------
__global__ void cvt_weights(const float* __restrict__ Win, const float* __restrict__ Wih,
                            const float* __restrict__ Whh, const float* __restrict__ Wout,
                            f16* __restrict__ dst) {
  int i = blockIdx.x * blockDim.x + threadIdx.x;
  if (i < 32768) {
    float v = Win[i]; f16 h = (f16)v;
    dst[i] = h; dst[32768 + i] = (f16)(v - (float)h);
  } else if (i < 98304) {
    int j = i - 32768; float v = Wih[j]; f16 h = (f16)v;
    dst[65536 + j] = h; dst[131072 + j] = (f16)(v - (float)h);
  } else if (i < 163840) {
    int j = i - 98304; dst[196608 + j] = (f16)(CSC * Whh[j]);
  } else if (i < 196608) {
    int j = i - 163840; dst[262144 + j] = (f16)Wout[j];
  }
}

// ---------------------------------------------------------------------------
// GEMM: C[m,n] = act( sum_k A[m,k]*W[n,k] + bias[n] )   (baseline, proven)
// ---------------------------------------------------------------------------
constexpr int BM = 64, BN = 64, BK = 64;

template<int MODE>
__global__ __launch_bounds__(256)
void gemm_kernel(const void* __restrict__ Ap, const void* __restrict__ Ap2,
                 const f16* __restrict__ Bh_, const f16* __restrict__ Bl_,
                 const float* __restrict__ bias, const float* __restrict__ bias2,
                 void* __restrict__ Cp, void* __restrict__ Cp2,
                 int K, int N) {
  __shared__ __align__(16) f16 Ah[BM][BK + 8];
  __shared__ __align__(16) f16 Al[BM][BK + 8];
  __shared__ __align__(16) f16 Bh[BN][BK + 8];
  __shared__ __align__(16) f16 Bl[BN][BK + 8];

  const int tid  = threadIdx.x;
  const int lane = tid & 63;
  const int wid  = tid >> 6;
  const int wm = wid >> 1, wn = wid & 1;
  const long row0 = (long)blockIdx.x * BM;
  const int  col0 = blockIdx.y * BN;
  const int r  = tid >> 2;
  const int cc = (tid & 3) * 16;

  f32x4 acc[2][2] = {};

  for (int k0 = 0; k0 < K; k0 += BK) {
    if constexpr (MODE == 1) {
      const float* src = (const float*)Ap + (row0 + r) * (long)K + k0 + cc;
      #pragma unroll
      for (int q = 0; q < 4; ++q) {
        float4 v = ((const float4*)src)[q];
        f16 h0 = (f16)v.x, h1 = (f16)v.y, h2 = (f16)v.z, h3 = (f16)v.w;
        Ah[r][cc + 4*q + 0] = h0;  Al[r][cc + 4*q + 0] = (f16)(v.x - (float)h0);
        Ah[r][cc + 4*q + 1] = h1;  Al[r][cc + 4*q + 1] = (f16)(v.y - (float)h1);
        Ah[r][cc + 4*q + 2] = h2;  Al[r][cc + 4*q + 2] = (f16)(v.z - (float)h2);
        Ah[r][cc + 4*q + 3] = h3;  Al[r][cc + 4*q + 3] = (f16)(v.w - (float)h3);
      }
    } else if constexpr (MODE == 2) {
      const f16* sh = (const f16*)Ap  + (row0 + r) * (long)K + k0 + cc;
      const f16* sl = (const f16*)Ap2 + (row0 + r) * (long)K + k0 + cc;
      *(uint4*)&Ah[r][cc]     = *(const uint4*)sh;
      *(uint4*)&Ah[r][cc + 8] = *(const uint4*)(sh + 8);
      *(uint4*)&Al[r][cc]     = *(const uint4*)sl;
      *(uint4*)&Al[r][cc + 8] = *(const uint4*)(sl + 8);
    } else {
      const f16* sh = (const f16*)Ap + (row0 + r) * (long)K + k0 + cc;
      *(uint4*)&Ah[r][cc]     = *(const uint4*)sh;
      *(uint4*)&Ah[r][cc + 8] = *(const uint4*)(sh + 8);
    }
    {
      const f16* sh = Bh_ + (col0 + r) * (long)K + k0 + cc;
      *(uint4*)&Bh[r][cc]     = *(const uint4*)sh;
      *(uint4*)&Bh[r][cc + 8] = *(const uint4*)(sh + 8);
      if constexpr (MODE != 3) {
        const f16* sl = Bl_ + (col0 + r) * (long)K + k0 + cc;
        *(uint4*)&Bl[r][cc]     = *(const uint4*)sl;
        *(uint4*)&Bl[r][cc + 8] = *(const uint4*)(sl + 8);
      }
    }
    __syncthreads();

    #pragma unroll
    for (int ks = 0; ks < BK / 32; ++ks) {
      const int ko = ks * 32 + (lane >> 4) * 8;
      const int ra = wm * 32 + (lane & 15);
      const int rb = wn * 32 + (lane & 15);
      f16x8 a0 = *(const f16x8*)&Ah[ra][ko];
      f16x8 a1 = *(const f16x8*)&Ah[ra + 16][ko];
      f16x8 b0 = *(const f16x8*)&Bh[rb][ko];
      f16x8 b1 = *(const f16x8*)&Bh[rb + 16][ko];
      acc[0][0] = __builtin_amdgcn_mfma_f32_16x16x32_f16(a0, b0, acc[0][0], 0, 0, 0);
      acc[0][1] = __builtin_amdgcn_mfma_f32_16x16x32_f16(a0, b1, acc[0][1], 0, 0, 0);
      acc[1][0] = __builtin_amdgcn_mfma_f32_16x16x32_f16(a1, b0, acc[1][0], 0, 0, 0);
      acc[1][1] = __builtin_amdgcn_mfma_f32_16x16x32_f16(a1, b1, acc[1][1], 0, 0, 0);
      if constexpr (MODE != 3) {
        f16x8 la0 = *(const f16x8*)&Al[ra][ko];
        f16x8 la1 = *(const f16x8*)&Al[ra + 16][ko];
        f16x8 lb0 = *(const f16x8*)&Bl[rb][ko];
        f16x8 lb1 = *(const f16x8*)&Bl[rb + 16][ko];
        acc[0][0] = __builtin_amdgcn_mfma_f32_16x16x32_f16(a0, lb0, acc[0][0], 0, 0, 0);
        acc[0][0] = __builtin_amdgcn_mfma_f32_16x16x32_f16(la0, b0, acc[0][0], 0, 0, 0);
        acc[0][1] = __builtin_amdgcn_mfma_f32_16x16x32_f16(a0, lb1, acc[0][1], 0, 0, 0);
        acc[0][1] = __builtin_amdgcn_mfma_f32_16x16x32_f16(la0, b1, acc[0][1], 0, 0, 0);
        acc[1][0] = __builtin_amdgcn_mfma_f32_16x16x32_f16(a1, lb0, acc[1][0], 0, 0, 0);
        acc[1][0] = __builtin_amdgcn_mfma_f32_16x16x32_f16(la1, b0, acc[1][0], 0, 0, 0);
        acc[1][1] = __builtin_amdgcn_mfma_f32_16x16x32_f16(a1, lb1, acc[1][1], 0, 0, 0);
        acc[1][1] = __builtin_amdgcn_mfma_f32_16x16x32_f16(la1, b1, acc[1][1], 0, 0, 0);
      }
    }
    __syncthreads();
  }

  #pragma unroll
  for (int mi = 0; mi < 2; ++mi)
    #pragma unroll
    for (int ni = 0; ni < 2; ++ni)
      #pragma unroll
      for (int q = 0; q < 4; ++q) {
        long row = row0 + wm * 32 + mi * 16 + (lane >> 4) * 4 + q;
        int  col = col0 + wn * 32 + ni * 16 + (lane & 15);
        if constexpr (MODE == 1) {
          float v = fmaxf(acc[mi][ni][q] + bias[col], 0.0f);
          f16 h = (f16)v;
          ((f16*)Cp )[row * (long)N + col] = h;
          ((f16*)Cp2)[row * (long)N + col] = (f16)(v - (float)h);
        } else if constexpr (MODE == 2) {
          float v = (acc[mi][ni][q] + bias[col] + bias2[col]) * CSC;
          ((float*)Cp)[row * (long)N + col] = v;
        } else {
          ((float*)Cp)[row * (long)N + col] = acc[mi][ni][q] + bias[col];
        }
      }
}

// ---------------------------------------------------------------------------
// Recurrence R15: fdot2/64-block structure (proven 887us shape), but the
// reduction group widens 4->8 lanes via xor set {1,2,32}: xor1/xor2 via
// quad-perm DPP, xor32 via v_permlane32_swap (VALU, gfx950). Rationale from
// R14's counters: the old kernel was LDS-INSTRUCTION-bound (64 ds_read_b128
// per CU-step ~= 768 cyc at ~12cyc/b128 [m134], vs only 256 cyc of fdot2
// issue). Halving each lane's k-slice to 32 (64B = 4 b128 reads) halves the
// LDS pipe to ~32 reads+8 b16 writes ~= 430 cyc/step.
//   lane: slice jj = (l&3)|((l>>5)<<2) owns k [32jj,32jj+32)
//         G8 = ((l>>2)&7)|(w<<3) owns outputs {4G8..4G8+3}
//         final owned output g = 32w + (l&31), dup pair (l, l^32)
//   reduce: stage1 xor1 keep/send (4->2 sums), stage2 xor2 keep/send (2->1),
//           stage3 xor32 all-reduce (permlane32_swap).
//   chunk rotation (q+jj)&3 on reads: per-instr bank aliasing is 2-way only
//   (free, m136). lane<32 writes LDS next-h; lane>=32 writes h16 global.
// 4-step unroll, rolling 4-deep pre prefetch (+1024/iter; last prefetches
// read <=3KB past pre into the weights region of ws — allocated, unused).
// lgkmcnt-only barriers. pre layout [b][t][g] (GEMM2 epilogue reverted).
// ---------------------------------------------------------------------------
#define STEP(K, SRC, DST, P) do {                                            \
  unsigned int hs[16];                                                       \
  _Pragma("unroll")                                                          \
  for (int q = 0; q < 4; ++q) {                                              \
    uint4 v = *(const uint4*)((SRC) + roff[q]);                              \
    hs[4*q+0] = v.x; hs[4*q+1] = v.y; hs[4*q+2] = v.z; hs[4*q+3] = v.w;      \
  }                                                                          \
  float sA0 = 0.f, sA1 = 0.f, sA2 = 0.f, sA3 = 0.f;                          \
  float sB0 = 0.f, sB1 = 0.f, sB2 = 0.f, sB3 = 0.f;                          \
  _Pragma("unroll")                                                          \
  for (int m = 0; m < 8; ++m) {                                              \
    sA0 = fdot2f(wr[0][m], hs[m], sA0);                                      \
    sA1 = fdot2f(wr[1][m], hs[m], sA1);                                      \
    sA2 = fdot2f(wr[2][m], hs[m], sA2);                                      \
    sA3 = fdot2f(wr[3][m], hs[m], sA3);                                      \
  }                                                                          \
  _Pragma("unroll")                                                          \
  for (int m = 8; m < 16; ++m) {                                             \
    sB0 = fdot2f(wr[0][m], hs[m], sB0);                                      \
    sB1 = fdot2f(wr[1][m], hs[m], sB1);                                      \
    sB2 = fdot2f(wr[2][m], hs[m], sB2);                                      \
    sB3 = fdot2f(wr[3][m], hs[m], sB3);                                      \
  }                                                                          \
  float sv0 = sA0 + sB0, sv1 = sA1 + sB1;                                    \
  float sv2 = sA2 + sB2, sv3 = sA3 + sB3;                                    \
  /* stage1 xor1: keep outputs with (i&1)==s0 */                             \
  float k0 = s0 ? sv1 : sv0, d0 = s0 ? sv0 : sv1;                            \
  float k1 = s0 ? sv3 : sv2, d1 = s0 ? sv2 : sv3;                            \
  float t0 = k0 + dpp_xor<0xB1>(d0);                                         \
  float t1 = k1 + dpp_xor<0xB1>(d1);                                         \
  /* stage2 xor2: keep t[s1] -> output 2*s1+s0 */                            \
  float rk = s1 ? t1 : t0, rs = s1 ? t0 : t1;                                \
  float z2 = rk + dpp_xor<0x4E>(rs);                                         \
  /* stage3 xor32 all-reduce */                                              \
  float z  = z2 + xor32_partner(z2, lane) + (P);                             \
  float ee = exp2f_hw(z);                                                    \
  float hv = fmaxf(fmaf(-2.0f, rcp_hw(ee + 1.0f), 1.0f), 0.0f);              \
  f16 hf = (f16)hv;                                                          \
  if (lane < 32) *(f16*)((DST) + wo) = hf;     /* LDS next-h (one copy) */   \
  else           hp[(K) * 256] = hf;           /* h16 global (other copy) */ \
} while (0)

__global__ __launch_bounds__(512, 1)
void rec_kernel(const float* __restrict__ pre, const f16* __restrict__ W2,
                f16* __restrict__ h16) {
  const int b    = blockIdx.x;
  const int tid  = threadIdx.x;
  const int lane = tid & 63;
  const int w    = tid >> 6;                       // 0..7
  const int jj   = (lane & 3) | ((lane >> 5) << 2); // slice 0..7: k [32jj,32jj+32)
  const int s0   = lane & 1;
  const int s1   = (lane >> 1) & 1;
  const int G8   = ((lane >> 2) & 7) | (w << 3);   // 0..63: outputs 4G8..4G8+3
  const int g    = 32 * w + (lane & 31);           // owned output (dup with l^32)

  __shared__ __align__(16) char hb[2][512];

  // W rows 4G8+i, k slice [32jj,32jj+32), chunk order c=(q+jj)&3 to match reads
  unsigned int wr[4][16];
  #pragma unroll
  for (int i = 0; i < 4; ++i)
    #pragma unroll
    for (int q = 0; q < 4; ++q) {
      int c = (q + jj) & 3;
      uint4 v = *(const uint4*)(W2 + (size_t)(4 * G8 + i) * 256 + 32 * jj + 8 * c);
      wr[i][4*q+0] = v.x; wr[i][4*q+1] = v.y; wr[i][4*q+2] = v.z; wr[i][4*q+3] = v.w;
    }
  if (tid < 128) ((unsigned int*)&hb[0][0])[tid] = 0u;
  __syncthreads();

  int roff[4];
  #pragma unroll
  for (int q = 0; q < 4; ++q) roff[q] = 64 * jj + 16 * ((q + jj) & 3);
  const int wo = 2 * g;

  const float* pp  = pre + (size_t)b * TLEN * 256 + g;
  f16*         hp  = h16 + (size_t)b * TLEN * 256 + g;
  const float* ppf = pp + 1024;              // t+4 prefetch pointer

  float p0 = pp[0];
  float p1 = pp[256];
  float p2 = pp[512];
  float p3 = pp[768];

  const char* hb0 = &hb[0][0];
  char*       hb1 = &hb[1][0];

  #pragma unroll 1
  for (int t = 0; t < TLEN; t += 4) {
    // issue next-quad prefetch early; lands during these 4 steps
    float n0 = ppf[0];
    float n1 = ppf[256];
    float n2 = ppf[512];
    float n3 = ppf[768];
    STEP(0, hb0, hb1, p0);
    barrier_lds();
    STEP(1, hb1, (char*)hb0, p1);
    barrier_lds();
    STEP(2, hb0, hb1, p2);
    barrier_lds();
    STEP(3, hb1, (char*)hb0, p3);
    barrier_lds();
    p0 = n0; p1 = n1; p2 = n2; p3 = n3;
    ppf += 1024;
    hp  += 1024;
  }
}

// ---------------------------------------------------------------------------
// h16 -> f32 hidden (parallel, HBM-bound; removes the f32 store from rec's
// serial loop). Proven in R2.
// ---------------------------------------------------------------------------
__global__ __launch_bounds__(256)
void cvt_h(const f16* __restrict__ src, float* __restrict__ dst, long n) {
  long i0 = ((long)blockIdx.x * 256 + threadIdx.x) * 8;
  long stride = (long)gridDim.x * 256 * 8;
  for (long i = i0; i < n; i += stride) {
    f16x8 v = *(const f16x8*)(src + i);
    float4 a = {(float)v[0], (float)v[1], (float)v[2], (float)v[3]};
    float4 bq = {(float)v[4], (float)v[5], (float)v[6], (float)v[7]};
    *(float4*)(dst + i) = a;
    *(float4*)(dst + i + 4) = bq;
  }
}

// ---------------------------------------------------------------------------
extern "C" void kernel_launch(void* const* d_in, const int* in_sizes, int n_in,
                              void* d_out, int out_size, void* d_ws, size_t ws_size,
                              hipStream_t stream) {
  const float* input = (const float*)d_in[0];
  const float* W_in  = (const float*)d_in[1];
  const float* b_in  = (const float*)d_in[2];
  const float* W_ih  = (const float*)d_in[3];
  const float* b_ih  = (const float*)d_in[4];
  const float* W_hh  = (const float*)d_in[5];
  const float* b_hh  = (const float*)d_in[6];
  const float* W_out = (const float*)d_in[7];
  const float* b_out = (const float*)d_in[8];

  float* hidden = (float*)d_out;                   // [64,2048,256] f32
  float* outp   = (float*)d_out + MROWS * NHID;    // [64,2048,128] f32

  char* ws = (char*)d_ws;
  const size_t xh_off  = 0;
  const size_t xl_off  = (size_t)MROWS * NHID * 2;       // 64 MiB
  const size_t pre_off = xl_off * 2;                     // 128 MiB in
  const size_t w_off   = pre_off + (size_t)MROWS * NHID * 4;
  const size_t need    = w_off + 294912ull * 2;
  if (ws_size < need) return;

  f16*   x_hi  = (f16*)(ws + xh_off);
  f16*   x_lo  = (f16*)(ws + xl_off);
  float* pre   = (float*)(ws + pre_off);                 // plain [b][t][g], scaled
  f16*   wbase = (f16*)(ws + w_off);
  f16 *WinH = wbase,           *WinL = wbase + 32768;
  f16 *WihH = wbase + 65536,   *WihL = wbase + 131072;
  f16 *Whh16 = wbase + 196608, *Wout16 = wbase + 262144;
  f16* h16 = x_hi;   // alias: x consumed by G2 before rec writes h16

  cvt_weights<<<768, 256, 0, stream>>>(W_in, W_ih, W_hh, W_out, wbase);

  dim3 g12((unsigned)(MROWS / BM), NHID / BN);
  gemm_kernel<1><<<g12, 256, 0, stream>>>(input, nullptr, WinH, WinL, b_in, nullptr,
                                          x_hi, x_lo, NIN, NHID);
  gemm_kernel<2><<<g12, 256, 0, stream>>>(x_hi, x_lo, WihH, WihL, b_ih, b_hh,
                                          pre, nullptr, NHID, NHID);

  rec_kernel<<<BATCH, 512, 0, stream>>>(pre, Whh16, h16);

  cvt_h<<<2048, 256, 0, stream>>>(h16, hidden, MROWS * NHID);

  dim3 g3((unsigned)(MROWS / BM), NOUT / BN);
  gemm_kernel<3><<<g3, 256, 0, stream>>>(h16, nullptr, Wout16, nullptr, b_out, nullptr,
                                         outp, nullptr, NHID, NOUT);
}

// Round 4
// 1191.270 us; speedup vs baseline: 1.6657x; 1.0026x over previous
//
#include <hip/hip_runtime.h>
#include <hip/hip_fp16.h>

typedef _Float16 f16;
typedef __attribute__((ext_vector_type(2))) _Float16 f16x2;
typedef __attribute__((ext_vector_type(8))) _Float16 f16x8;
typedef __attribute__((ext_vector_type(4))) float f32x4;
typedef __attribute__((ext_vector_type(16))) unsigned int u32x16;

constexpr int BATCH = 64;
constexpr int TLEN  = 2048;
constexpr int NIN   = 128;
constexpr int NHID  = 256;
constexpr int NOUT  = 128;
constexpr long MROWS = (long)BATCH * TLEN;   // 131072
constexpr float CSC = 2.8853900817779268f;   // 2*log2(e): 2^(CSC*z) = e^(2z)

__device__ __forceinline__ float exp2f_hw(float x) {
#if __has_builtin(__builtin_amdgcn_exp2f)
  return __builtin_amdgcn_exp2f(x);
#else
  return __expf(x * 0.6931471805599453f);
#endif
}
__device__ __forceinline__ float rcp_hw(float x) {
#if __has_builtin(__builtin_amdgcn_rcpf)
  return __builtin_amdgcn_rcpf(x);
#else
  return 1.0f / x;
#endif
}
__device__ __forceinline__ float fdot2f(unsigned int a, unsigned int b, float c) {
#if __has_builtin(__builtin_amdgcn_fdot2)
  return __builtin_amdgcn_fdot2(__builtin_bit_cast(f16x2, a),
                                __builtin_bit_cast(f16x2, b), c, false);
#else
  f16x2 av = __builtin_bit_cast(f16x2, a);
  f16x2 bv = __builtin_bit_cast(f16x2, b);
  return c + (float)av.x * (float)bv.x + (float)av.y * (float)bv.y;
#endif
}
// DPP: 0xB1 = quad_perm(1,0,3,2) -> lane^1 ; 0x4E = quad_perm(2,3,0,1) -> lane^2
template<int CTRL>
__device__ __forceinline__ float dpp_xor(float x) {
  int r = __builtin_amdgcn_update_dpp(0, __builtin_bit_cast(int, x),
                                      CTRL, 0xF, 0xF, true);
  return __builtin_bit_cast(float, r);
}
// partner value across lane^32 (VALU permlane on gfx950; LDS bpermute fallback)
__device__ __forceinline__ float xor32_partner(float x, int lane) {
#if __has_builtin(__builtin_amdgcn_permlane32_swap)
  auto r = __builtin_amdgcn_permlane32_swap(
      __builtin_bit_cast(unsigned int, x), __builtin_bit_cast(unsigned int, x),
      false, false);
  unsigned int pv = (lane < 32) ? r[1] : r[0];  // r[0]=new_vdst, r[1]=new_src0
  return __builtin_bit_cast(float, pv);
#else
  return __builtin_bit_cast(float, __builtin_amdgcn_ds_bpermute(
      ((lane ^ 32) << 2), __builtin_bit_cast(int, x)));
#endif
}
// barrier that makes LDS writes visible WITHOUT draining vmcnt (global
// stores / prefetch loads keep flying across steps)
__device__ __forceinline__ void barrier_lds() {
  asm volatile("s_waitcnt lgkmcnt(0)" ::: "memory");
  __builtin_amdgcn_s_barrier();
  asm volatile("" ::: "memory");
}

// ---------------------------------------------------------------------------
// Weight convert + hi/lo split. Whh pre-scaled by CSC (tanh exp2 fold).
// f16 layout: WinH[32768] WinL[32768] WihH[65536] WihL[65536] Whh[65536] Wout[32768]
// ---------------------------------------------------------------------------
__global__ void cvt_weights(const float* __restrict__ Win, const float* __restrict__ Wih,
                            const float* __restrict__ Whh, const float* __restrict__ Wout,
                            f16* __restrict__ dst) {
  int i = blockIdx.x * blockDim.x + threadIdx.x;
  if (i < 32768) {
    float v = Win[i]; f16 h = (f16)v;
    dst[i] = h; dst[32768 + i] = (f16)(v - (float)h);
  } else if (i < 98304) {
    int j = i - 32768; float v = Wih[j]; f16 h = (f16)v;
    dst[65536 + j] = h; dst[131072 + j] = (f16)(v - (float)h);
  } else if (i < 163840) {
    int j = i - 98304; dst[196608 + j] = (f16)(CSC * Whh[j]);
  } else if (i < 196608) {
    int j = i - 163840; dst[262144 + j] = (f16)Wout[j];
  }
}

// ---------------------------------------------------------------------------
// GEMM: C[m,n] = act( sum_k A[m,k]*W[n,k] + bias[n] )   (baseline, proven)
// ---------------------------------------------------------------------------
constexpr int BM = 64, BN = 64, BK = 64;

template<int MODE>
__global__ __launch_bounds__(256)
void gemm_kernel(const void* __restrict__ Ap, const void* __restrict__ Ap2,
                 const f16* __restrict__ Bh_, const f16* __restrict__ Bl_,
                 const float* __restrict__ bias, const float* __restrict__ bias2,
                 void* __restrict__ Cp, void* __restrict__ Cp2,
                 int K, int N) {
  __shared__ __align__(16) f16 Ah[BM][BK + 8];
  __shared__ __align__(16) f16 Al[BM][BK + 8];
  __shared__ __align__(16) f16 Bh[BN][BK + 8];
  __shared__ __align__(16) f16 Bl[BN][BK + 8];

  const int tid  = threadIdx.x;
  const int lane = tid & 63;
  const int wid  = tid >> 6;
  const int wm = wid >> 1, wn = wid & 1;
  const long row0 = (long)blockIdx.x * BM;
  const int  col0 = blockIdx.y * BN;
  const int r  = tid >> 2;
  const int cc = (tid & 3) * 16;

  f32x4 acc[2][2] = {};

  for (int k0 = 0; k0 < K; k0 += BK) {
    if constexpr (MODE == 1) {
      const float* src = (const float*)Ap + (row0 + r) * (long)K + k0 + cc;
      #pragma unroll
      for (int q = 0; q < 4; ++q) {
        float4 v = ((const float4*)src)[q];
        f16 h0 = (f16)v.x, h1 = (f16)v.y, h2 = (f16)v.z, h3 = (f16)v.w;
        Ah[r][cc + 4*q + 0] = h0;  Al[r][cc + 4*q + 0] = (f16)(v.x - (float)h0);
        Ah[r][cc + 4*q + 1] = h1;  Al[r][cc + 4*q + 1] = (f16)(v.y - (float)h1);
        Ah[r][cc + 4*q + 2] = h2;  Al[r][cc + 4*q + 2] = (f16)(v.z - (float)h2);
        Ah[r][cc + 4*q + 3] = h3;  Al[r][cc + 4*q + 3] = (f16)(v.w - (float)h3);
      }
    } else if constexpr (MODE == 2) {
      const f16* sh = (const f16*)Ap  + (row0 + r) * (long)K + k0 + cc;
      const f16* sl = (const f16*)Ap2 + (row0 + r) * (long)K + k0 + cc;
      *(uint4*)&Ah[r][cc]     = *(const uint4*)sh;
      *(uint4*)&Ah[r][cc + 8] = *(const uint4*)(sh + 8);
      *(uint4*)&Al[r][cc]     = *(const uint4*)sl;
      *(uint4*)&Al[r][cc + 8] = *(const uint4*)(sl + 8);
    } else {
      const f16* sh = (const f16*)Ap + (row0 + r) * (long)K + k0 + cc;
      *(uint4*)&Ah[r][cc]     = *(const uint4*)sh;
      *(uint4*)&Ah[r][cc + 8] = *(const uint4*)(sh + 8);
    }
    {
      const f16* sh = Bh_ + (col0 + r) * (long)K + k0 + cc;
      *(uint4*)&Bh[r][cc]     = *(const uint4*)sh;
      *(uint4*)&Bh[r][cc + 8] = *(const uint4*)(sh + 8);
      if constexpr (MODE != 3) {
        const f16* sl = Bl_ + (col0 + r) * (long)K + k0 + cc;
        *(uint4*)&Bl[r][cc]     = *(const uint4*)sl;
        *(uint4*)&Bl[r][cc + 8] = *(const uint4*)(sl + 8);
      }
    }
    __syncthreads();

    #pragma unroll
    for (int ks = 0; ks < BK / 32; ++ks) {
      const int ko = ks * 32 + (lane >> 4) * 8;
      const int ra = wm * 32 + (lane & 15);
      const int rb = wn * 32 + (lane & 15);
      f16x8 a0 = *(const f16x8*)&Ah[ra][ko];
      f16x8 a1 = *(const f16x8*)&Ah[ra + 16][ko];
      f16x8 b0 = *(const f16x8*)&Bh[rb][ko];
      f16x8 b1 = *(const f16x8*)&Bh[rb + 16][ko];
      acc[0][0] = __builtin_amdgcn_mfma_f32_16x16x32_f16(a0, b0, acc[0][0], 0, 0, 0);
      acc[0][1] = __builtin_amdgcn_mfma_f32_16x16x32_f16(a0, b1, acc[0][1], 0, 0, 0);
      acc[1][0] = __builtin_amdgcn_mfma_f32_16x16x32_f16(a1, b0, acc[1][0], 0, 0, 0);
      acc[1][1] = __builtin_amdgcn_mfma_f32_16x16x32_f16(a1, b1, acc[1][1], 0, 0, 0);
      if constexpr (MODE != 3) {
        f16x8 la0 = *(const f16x8*)&Al[ra][ko];
        f16x8 la1 = *(const f16x8*)&Al[ra + 16][ko];
        f16x8 lb0 = *(const f16x8*)&Bl[rb][ko];
        f16x8 lb1 = *(const f16x8*)&Bl[rb + 16][ko];
        acc[0][0] = __builtin_amdgcn_mfma_f32_16x16x32_f16(a0, lb0, acc[0][0], 0, 0, 0);
        acc[0][0] = __builtin_amdgcn_mfma_f32_16x16x32_f16(la0, b0, acc[0][0], 0, 0, 0);
        acc[0][1] = __builtin_amdgcn_mfma_f32_16x16x32_f16(a0, lb1, acc[0][1], 0, 0, 0);
        acc[0][1] = __builtin_amdgcn_mfma_f32_16x16x32_f16(la0, b1, acc[0][1], 0, 0, 0);
        acc[1][0] = __builtin_amdgcn_mfma_f32_16x16x32_f16(a1, lb0, acc[1][0], 0, 0, 0);
        acc[1][0] = __builtin_amdgcn_mfma_f32_16x16x32_f16(la1, b0, acc[1][0], 0, 0, 0);
        acc[1][1] = __builtin_amdgcn_mfma_f32_16x16x32_f16(a1, lb1, acc[1][1], 0, 0, 0);
        acc[1][1] = __builtin_amdgcn_mfma_f32_16x16x32_f16(la1, b1, acc[1][1], 0, 0, 0);
      }
    }
    __syncthreads();
  }

  #pragma unroll
  for (int mi = 0; mi < 2; ++mi)
    #pragma unroll
    for (int ni = 0; ni < 2; ++ni)
      #pragma unroll
      for (int q = 0; q < 4; ++q) {
        long row = row0 + wm * 32 + mi * 16 + (lane >> 4) * 4 + q;
        int  col = col0 + wn * 32 + ni * 16 + (lane & 15);
        if constexpr (MODE == 1) {
          float v = fmaxf(acc[mi][ni][q] + bias[col], 0.0f);
          f16 h = (f16)v;
          ((f16*)Cp )[row * (long)N + col] = h;
          ((f16*)Cp2)[row * (long)N + col] = (f16)(v - (float)h);
        } else if constexpr (MODE == 2) {
          float v = (acc[mi][ni][q] + bias[col] + bias2[col]) * CSC;
          ((float*)Cp)[row * (long)N + col] = v;
        } else {
          ((float*)Cp)[row * (long)N + col] = acc[mi][ni][q] + bias[col];
        }
      }
}

// ---------------------------------------------------------------------------
// Recurrence R16 = R15 shape + FORCED register residency of Whh.
// Diagnosis from R12/R15 counters: VGPR_Count 48/52 << the 64 weight words
// declared per lane -> the allocator REMATERIALIZED the invariant W2 loads
// into the t-loop (legal for const __restrict__ loads), i.e. every step
// re-loads 64 words/lane from L1/L2 (16 b128 VMEM/lane/step, ~128 VMEM and
// ~128KB per CU-step). That memory-pipe occupancy+latency (~1000 cyc) — not
// VALU, not LDS — set the ~1040-1148 cyc step time of BOTH variants, which
// is why halving LDS reads (R15) changed nothing.
// Fix: weights in four named u32x16 ext-vector SSA values, pinned by an
// opaque asm "+v" barrier after the load -> remat is illegal, values must
// stay in VGPRs (~130 total, budget 256/wave at 2 waves/SIMD).
// Everything else identical to R15 (passed, absmax 0.0039):
//   lane: slice jj owns k [32jj,32jj+32); G8 owns outputs {4G8..4G8+3};
//   reduce xor1/xor2 (DPP) + xor32 (permlane32_swap); chunk-rotated LDS
//   reads (0 conflicts measured); lane<32 writes LDS h, lane>=32 writes h16;
//   4-step unroll, rolling 4-deep pre prefetch, lgkmcnt-only barriers.
// ---------------------------------------------------------------------------
#define STEP(K, SRC, DST, P) do {                                            \
  unsigned int hs[16];                                                       \
  _Pragma("unroll")                                                          \
  for (int q = 0; q < 4; ++q) {                                              \
    uint4 v = *(const uint4*)((SRC) + roff[q]);                              \
    hs[4*q+0] = v.x; hs[4*q+1] = v.y; hs[4*q+2] = v.z; hs[4*q+3] = v.w;      \
  }                                                                          \
  float sA0 = 0.f, sA1 = 0.f, sA2 = 0.f, sA3 = 0.f;                          \
  float sB0 = 0.f, sB1 = 0.f, sB2 = 0.f, sB3 = 0.f;                          \
  _Pragma("unroll")                                                          \
  for (int m = 0; m < 8; ++m) {                                              \
    sA0 = fdot2f(wr0v[m], hs[m], sA0);                                      \
    sA1 = fdot2f(wr1v[m], hs[m], sA1);                                      \
    sA2 = fdot2f(wr2v[m], hs[m], sA2);                                      \
    sA3 = fdot2f(wr3v[m], hs[m], sA3);                                      \
  }                                                                          \
  _Pragma("unroll")                                                          \
  for (int m = 8; m < 16; ++m) {                                             \
    sB0 = fdot2f(wr0v[m], hs[m], sB0);                                      \
    sB1 = fdot2f(wr1v[m], hs[m], sB1);                                      \
    sB2 = fdot2f(wr2v[m], hs[m], sB2);                                      \
    sB3 = fdot2f(wr3v[m], hs[m], sB3);                                      \
  }                                                                          \
  float sv0 = sA0 + sB0, sv1 = sA1 + sB1;                                    \
  float sv2 = sA2 + sB2, sv3 = sA3 + sB3;                                    \
  /* stage1 xor1: keep outputs with (i&1)==s0 */                             \
  float k0 = s0 ? sv1 : sv0, d0 = s0 ? sv0 : sv1;                            \
  float k1 = s0 ? sv3 : sv2, d1 = s0 ? sv2 : sv3;                            \
  float t0 = k0 + dpp_xor<0xB1>(d0);                                         \
  float t1 = k1 + dpp_xor<0xB1>(d1);                                         \
  /* stage2 xor2: keep t[s1] -> output 2*s1+s0 */                            \
  float rk = s1 ? t1 : t0, rs = s1 ? t0 : t1;                                \
  float z2 = rk + dpp_xor<0x4E>(rs);                                         \
  /* stage3 xor32 all-reduce */                                              \
  float z  = z2 + xor32_partner(z2, lane) + (P);                             \
  float ee = exp2f_hw(z);                                                    \
  float hv = fmaxf(fmaf(-2.0f, rcp_hw(ee + 1.0f), 1.0f), 0.0f);              \
  f16 hf = (f16)hv;                                                          \
  if (lane < 32) *(f16*)((DST) + wo) = hf;     /* LDS next-h (one copy) */   \
  else           hp[(K) * 256] = hf;           /* h16 global (other copy) */ \
} while (0)

#define LOADW(dst, i) do {                                                   \
  _Pragma("unroll")                                                          \
  for (int q = 0; q < 4; ++q) {                                              \
    int c = (q + jj) & 3;                                                    \
    uint4 v = *(const uint4*)(W2 + (size_t)(4 * G8 + (i)) * 256              \
                              + 32 * jj + 8 * c);                            \
    dst[4*q+0] = v.x; dst[4*q+1] = v.y; dst[4*q+2] = v.z; dst[4*q+3] = v.w;  \
  }                                                                          \
} while (0)

__global__ __launch_bounds__(512, 1)
void rec_kernel(const float* __restrict__ pre, const f16* __restrict__ W2,
                f16* __restrict__ h16) {
  const int b    = blockIdx.x;
  const int tid  = threadIdx.x;
  const int lane = tid & 63;
  const int w    = tid >> 6;                       // 0..7
  const int jj   = (lane & 3) | ((lane >> 5) << 2); // slice 0..7: k [32jj,32jj+32)
  const int s0   = lane & 1;
  const int s1   = (lane >> 1) & 1;
  const int G8   = ((lane >> 2) & 7) | (w << 3);   // 0..63: outputs 4G8..4G8+3
  const int g    = 32 * w + (lane & 31);           // owned output (dup with l^32)

  __shared__ __align__(16) char hb[2][512];

  // W rows 4G8+i, k slice [32jj,32jj+32), chunk order c=(q+jj)&3 to match reads
  u32x16 wr0v, wr1v, wr2v, wr3v;
  LOADW(wr0v, 0);
  LOADW(wr1v, 1);
  LOADW(wr2v, 2);
  LOADW(wr3v, 3);
  // opaque barrier: values must be materialized in VGPRs here and cannot be
  // rematerialized (re-loaded) inside the t-loop by the register allocator.
  asm volatile("" : "+v"(wr0v), "+v"(wr1v), "+v"(wr2v), "+v"(wr3v));

  if (tid < 128) ((unsigned int*)&hb[0][0])[tid] = 0u;
  __syncthreads();

  int roff[4];
  #pragma unroll
  for (int q = 0; q < 4; ++q) roff[q] = 64 * jj + 16 * ((q + jj) & 3);
  const int wo = 2 * g;

  const float* pp  = pre + (size_t)b * TLEN * 256 + g;
  f16*         hp  = h16 + (size_t)b * TLEN * 256 + g;
  const float* ppf = pp + 1024;              // t+4 prefetch pointer

  float p0 = pp[0];
  float p1 = pp[256];
  float p2 = pp[512];
  float p3 = pp[768];

  const char* hb0 = &hb[0][0];
  char*       hb1 = &hb[1][0];

  #pragma unroll 1
  for (int t = 0; t < TLEN; t += 4) {
    // issue next-quad prefetch early; lands during these 4 steps
    float n0 = ppf[0];
    float n1 = ppf[256];
    float n2 = ppf[512];
    float n3 = ppf[768];
    STEP(0, hb0, hb1, p0);
    barrier_lds();
    STEP(1, hb1, (char*)hb0, p1);
    barrier_lds();
    STEP(2, hb0, hb1, p2);
    barrier_lds();
    STEP(3, hb1, (char*)hb0, p3);
    barrier_lds();
    p0 = n0; p1 = n1; p2 = n2; p3 = n3;
    ppf += 1024;
    hp  += 1024;
  }
}

// ---------------------------------------------------------------------------
// h16 -> f32 hidden (parallel, HBM-bound; removes the f32 store from rec's
// serial loop). Proven in R2.
// ---------------------------------------------------------------------------
__global__ __launch_bounds__(256)
void cvt_h(const f16* __restrict__ src, float* __restrict__ dst, long n) {
  long i0 = ((long)blockIdx.x * 256 + threadIdx.x) * 8;
  long stride = (long)gridDim.x * 256 * 8;
  for (long i = i0; i < n; i += stride) {
    f16x8 v = *(const f16x8*)(src + i);
    float4 a = {(float)v[0], (float)v[1], (float)v[2], (float)v[3]};
    float4 bq = {(float)v[4], (float)v[5], (float)v[6], (float)v[7]};
    *(float4*)(dst + i) = a;
    *(float4*)(dst + i + 4) = bq;
  }
}

// ---------------------------------------------------------------------------
extern "C" void kernel_launch(void* const* d_in, const int* in_sizes, int n_in,
                              void* d_out, int out_size, void* d_ws, size_t ws_size,
                              hipStream_t stream) {
  const float* input = (const float*)d_in[0];
  const float* W_in  = (const float*)d_in[1];
  const float* b_in  = (const float*)d_in[2];
  const float* W_ih  = (const float*)d_in[3];
  const float* b_ih  = (const float*)d_in[4];
  const float* W_hh  = (const float*)d_in[5];
  const float* b_hh  = (const float*)d_in[6];
  const float* W_out = (const float*)d_in[7];
  const float* b_out = (const float*)d_in[8];

  float* hidden = (float*)d_out;                   // [64,2048,256] f32
  float* outp   = (float*)d_out + MROWS * NHID;    // [64,2048,128] f32

  char* ws = (char*)d_ws;
  const size_t xh_off  = 0;
  const size_t xl_off  = (size_t)MROWS * NHID * 2;       // 64 MiB
  const size_t pre_off = xl_off * 2;                     // 128 MiB in
  const size_t w_off   = pre_off + (size_t)MROWS * NHID * 4;
  const size_t need    = w_off + 294912ull * 2;
  if (ws_size < need) return;

  f16*   x_hi  = (f16*)(ws + xh_off);
  f16*   x_lo  = (f16*)(ws + xl_off);
  float* pre   = (float*)(ws + pre_off);                 // plain [b][t][g], scaled
  f16*   wbase = (f16*)(ws + w_off);
  f16 *WinH = wbase,           *WinL = wbase + 32768;
  f16 *WihH = wbase + 65536,   *WihL = wbase + 131072;
  f16 *Whh16 = wbase + 196608, *Wout16 = wbase + 262144;
  f16* h16 = x_hi;   // alias: x consumed by G2 before rec writes h16

  cvt_weights<<<768, 256, 0, stream>>>(W_in, W_ih, W_hh, W_out, wbase);

  dim3 g12((unsigned)(MROWS / BM), NHID / BN);
  gemm_kernel<1><<<g12, 256, 0, stream>>>(input, nullptr, WinH, WinL, b_in, nullptr,
                                          x_hi, x_lo, NIN, NHID);
  gemm_kernel<2><<<g12, 256, 0, stream>>>(x_hi, x_lo, WihH, WihL, b_ih, b_hh,
                                          pre, nullptr, NHID, NHID);

  rec_kernel<<<BATCH, 512, 0, stream>>>(pre, Whh16, h16);

  cvt_h<<<2048, 256, 0, stream>>>(h16, hidden, MROWS * NHID);

  dim3 g3((unsigned)(MROWS / BM), NOUT / BN);
  gemm_kernel<3><<<g3, 256, 0, stream>>>(h16, nullptr, Wout16, nullptr, b_out, nullptr,
                                         outp, nullptr, NHID, NOUT);
}